// Round 13
// baseline (224.922 us; speedup 1.0000x reference)
//
#include <hip/hip_runtime.h>
#include <hip/hip_bf16.h>
#include <cstdint>

// Problem: B=64, D=1024, H=1024.
// act columns (6144): [0,1024) i_g | [1024,2048) f_g | [2048,3072) o_g
//                     [3072,4096) q | [4096,5120) k  | [5120,6144) v
// part layout (bf16): part[c][b][j], c = K-chunk of 256 (gates: 8 chunks;
// qkv: chunks 0..3 only)

#define NCOL 6144

typedef __attribute__((ext_vector_type(8))) short short8;
typedef __attribute__((ext_vector_type(4))) float f32x4;
typedef __attribute__((ext_vector_type(4))) unsigned short u16x4;

static __device__ __forceinline__ unsigned short f2bs(float f) {
    union { __hip_bfloat16 h; unsigned short s; } cv;
    cv.h = __float2bfloat16(f);          // RNE
    return cv.s;
}
static __device__ __forceinline__ u16x4 cvt4(f32x4 x) {
    u16x4 u; u[0]=f2bs(x[0]); u[1]=f2bs(x[1]); u[2]=f2bs(x[2]); u[3]=f2bs(x[3]);
    return u;
}
static __device__ __forceinline__ float b2f(unsigned short s) {
    union { uint32_t u; float f; } v; v.u = ((uint32_t)s) << 16; return v.f;
}

// ---------------- Kernel P: projections + fused chunk-reduction/activation ---
// R9/R12-proven proj structure (flat 576-block grid, dbuf K=64 sub-steps,
// bf16 part). NEW: last block per col-tile (device-scope fence + atomic
// counter) reduces the tile's chunks + bias + activation -> act. Removes the
// separate act kernel and one launch gap.
__global__ __launch_bounds__(256) void proj_kernel(
    const float* __restrict__ input, const float* __restrict__ hvec,
    const float* __restrict__ w_ih, const float* __restrict__ w_hh,
    const float* __restrict__ wq, const float* __restrict__ wk,
    const float* __restrict__ wv, const float* __restrict__ bias,
    const float* __restrict__ wq_b, const float* __restrict__ wk_b,
    const float* __restrict__ wv_b, unsigned short* __restrict__ part,
    float* __restrict__ act, unsigned int* __restrict__ cnt)
{
    int bid = blockIdx.x;           // 0..575 (384 gate items + 192 qkv items)
    int ct, c;
    if (bid < 384) { ct = bid >> 3; c = bid & 7; }
    else { int e = bid - 384; ct = 48 + (e >> 2); c = e & 3; }
    int jbase = ct * 64;
    int o = jbase >> 10;            // 0..5
    int jloc = jbase & 1023;
    int nchunk = (o < 3) ? 8 : 4;

    const float* W; const float* src; int koff; int wrow;
    if (o < 3) {
        wrow = o * 1024 + jloc;
        if (c < 4) { W = w_ih; src = input; koff = c * 256; }
        else       { W = w_hh; src = hvec;  koff = (c - 4) * 256; }
    } else {
        wrow = jloc;
        W = (o == 3) ? wq : (o == 4) ? wk : wv;
        src = input; koff = c * 256;
    }

    // bf16 sub-tiles [64 rows][64 K + 8 pad], double-buffered
    __shared__ unsigned short Als[2][64][72];
    __shared__ unsigned short Bls[2][64][72];
    __shared__ unsigned int oldc;

    int tid = threadIdx.x;
    int r0 = tid >> 4;              // staging row base 0..15 (+16*i)
    int kc = (tid & 15) << 2;       // float col 0..60

    f32x4 ra[4], rb[4];

    // prefetch sub-step 0
    #pragma unroll
    for (int i = 0; i < 4; ++i)
        ra[i] = *(const f32x4*)&src[(size_t)(r0 + 16 * i) * 1024 + koff + kc];
    #pragma unroll
    for (int i = 0; i < 4; ++i)
        rb[i] = *(const f32x4*)&W[(size_t)(wrow + r0 + 16 * i) * 1024 + koff + kc];
    #pragma unroll
    for (int i = 0; i < 4; ++i) *(u16x4*)&Als[0][r0 + 16 * i][kc] = cvt4(ra[i]);
    #pragma unroll
    for (int i = 0; i < 4; ++i) *(u16x4*)&Bls[0][r0 + 16 * i][kc] = cvt4(rb[i]);
    __syncthreads();

    int lane = tid & 63;
    int w    = tid >> 6;                    // wave -> col group
    int cn16 = lane & 15;
    int kg   = lane >> 4;                   // 0..3

    f32x4 acc[4];
    #pragma unroll
    for (int m = 0; m < 4; ++m) { acc[m][0]=0.f; acc[m][1]=0.f; acc[m][2]=0.f; acc[m][3]=0.f; }

    #pragma unroll
    for (int s = 0; s < 4; ++s) {
        if (s < 3) {                        // issue next sub-slab loads first
            int kof2 = koff + (s + 1) * 64 + kc;
            #pragma unroll
            for (int i = 0; i < 4; ++i)
                ra[i] = *(const f32x4*)&src[(size_t)(r0 + 16 * i) * 1024 + kof2];
            #pragma unroll
            for (int i = 0; i < 4; ++i)
                rb[i] = *(const f32x4*)&W[(size_t)(wrow + r0 + 16 * i) * 1024 + kof2];
        }

        int buf = s & 1;
        #pragma unroll
        for (int ks2 = 0; ks2 < 2; ++ks2) {
            int kb = ks2 * 32 + kg * 8;     // 16B-aligned
            short8 bf = *(const short8*)&Bls[buf][w * 16 + cn16][kb];
            #pragma unroll
            for (int m = 0; m < 4; ++m) {
                short8 af = *(const short8*)&Als[buf][m * 16 + cn16][kb];
                acc[m] = __builtin_amdgcn_mfma_f32_16x16x32_bf16(af, bf, acc[m], 0, 0, 0);
            }
        }

        if (s < 3) {
            int nb = (s + 1) & 1;
            #pragma unroll
            for (int i = 0; i < 4; ++i) *(u16x4*)&Als[nb][r0 + 16 * i][kc] = cvt4(ra[i]);
            #pragma unroll
            for (int i = 0; i < 4; ++i) *(u16x4*)&Bls[nb][r0 + 16 * i][kc] = cvt4(rb[i]);
        }
        __syncthreads();
    }

    // D layout: col = lane&15, row(batch) = kg*4 + reg (+ m*16); bf16 store
    #pragma unroll
    for (int m = 0; m < 4; ++m) {
        #pragma unroll
        for (int r = 0; r < 4; ++r) {
            int b = m * 16 + kg * 4 + r;
            part[((size_t)c * 64 + b) * NCOL + jbase + w * 16 + cn16] = f2bs(acc[m][r]);
        }
    }

    // ---- last-block-per-tile reduction + activation (canonical pattern) ----
    __threadfence();                 // release: make part stores visible
    __syncthreads();
    if (tid == 0) oldc = atomicAdd(&cnt[ct], 1u);
    __syncthreads();
    if (oldc == (unsigned)(nchunk - 1)) {
        __threadfence();             // acquire: discard stale lines
        int jg = (tid & 15) * 4;     // j offset within tile, 0..60
        int bg = (tid >> 4) * 4;     // batch base, 0..60
        const float* bp = (o < 3) ? (bias + jbase)
                                  : ((o == 3) ? wq_b : (o == 4) ? wk_b : wv_b) + jloc;
        f32x4 bb = *(const f32x4*)&bp[jg];
        #pragma unroll
        for (int bi = 0; bi < 4; ++bi) {
            int b = bg + bi;
            f32x4 s2 = bb;
            for (int c2 = 0; c2 < nchunk; ++c2) {
                u16x4 u = *(const u16x4*)&part[((size_t)c2 * 64 + b) * NCOL + jbase + jg];
                s2[0] += b2f(u[0]); s2[1] += b2f(u[1]);
                s2[2] += b2f(u[2]); s2[3] += b2f(u[3]);
            }
            f32x4 r;
            if (o < 2) {
                r[0]=expf(s2[0]); r[1]=expf(s2[1]); r[2]=expf(s2[2]); r[3]=expf(s2[3]);
            } else if (o == 2) {
                r[0]=1.f/(1.f+expf(-s2[0])); r[1]=1.f/(1.f+expf(-s2[1]));
                r[2]=1.f/(1.f+expf(-s2[2])); r[3]=1.f/(1.f+expf(-s2[3]));
            } else {
                r = s2;
            }
            *(f32x4*)&act[(size_t)b * NCOL + jbase + jg] = r;
        }
    }
}

// ---------------- Kernel U: c_new = f*c + (i*v)*k, fused q-weighted row sums -
// R12-proven: grid (16,64), grouped 8-load/8-store nt phases.
__global__ __launch_bounds__(256) void update_kernel(
    const float* __restrict__ c_in, const float* __restrict__ act,
    float* __restrict__ c_out, float* __restrict__ hpart)
{
    int t = blockIdx.x;            // 0..15
    int b = blockIdx.y;            // 0..63
    int tid = threadIdx.x;
    const float* arow = act + (size_t)b * NCOL;

    __shared__ float fs[64], ivs[64], qvs[64];
    if (tid < 64) {
        int hrow = t * 64 + tid;
        fs[tid]  = arow[1024 + hrow];
        ivs[tid] = arow[hrow] * arow[5120 + hrow];
        qvs[tid] = arow[3072 + hrow];
    }
    int col = tid * 4;
    f32x4 k4 = *(const f32x4*)&arow[4096 + col];
    __syncthreads();

    f32x4 acc; acc[0]=0.f; acc[1]=0.f; acc[2]=0.f; acc[3]=0.f;
    size_t base = ((size_t)b * 1024 + (size_t)t * 64) * 1024 + col;

    f32x4 cc[8];
    for (int g = 0; g < 8; ++g) {
        size_t gb = base + (size_t)g * 8 * 1024;
        #pragma unroll
        for (int i = 0; i < 8; ++i)
            cc[i] = __builtin_nontemporal_load((const f32x4*)(c_in + gb + (size_t)i * 1024));
        #pragma unroll
        for (int i = 0; i < 8; ++i) {
            int hh = g * 8 + i;
            float f = fs[hh], iv = ivs[hh], qv = qvs[hh];
            f32x4 cn = f * cc[i] + iv * k4;
            __builtin_nontemporal_store(cn, (f32x4*)(c_out + gb + (size_t)i * 1024));
            acc += qv * cn;
        }
    }
    *(f32x4*)&hpart[((size_t)b * 16 + t) * 1024 + col] = acc;
}

// ---------------- Kernel R: h_new = o_g * sum_t hpart ----------------
__global__ __launch_bounds__(256) void readout_kernel(
    const float* __restrict__ hpart, const float* __restrict__ act,
    float* __restrict__ h_new)
{
    int idx = blockIdx.x * 256 + threadIdx.x;   // 0..65536
    int b = idx >> 10, j = idx & 1023;
    float s = 0.f;
    #pragma unroll
    for (int t = 0; t < 16; ++t)
        s += hpart[((size_t)b * 16 + t) * 1024 + j];
    h_new[idx] = act[(size_t)b * NCOL + 2048 + j] * s;
}

extern "C" void kernel_launch(void* const* d_in, const int* in_sizes, int n_in,
                              void* d_out, int out_size, void* d_ws, size_t ws_size,
                              hipStream_t stream)
{
    (void)in_sizes; (void)n_in; (void)out_size; (void)ws_size;
    const float* input = (const float*)d_in[0];   // [64,1024]
    const float* hvec  = (const float*)d_in[1];   // [64,1024]
    const float* c_in  = (const float*)d_in[2];   // [64,1024,1024]
    const float* w_ih  = (const float*)d_in[3];   // [3072,1024]
    const float* w_hh  = (const float*)d_in[4];   // [3072,1024]
    const float* bias  = (const float*)d_in[5];   // [3072]
    const float* wq_w  = (const float*)d_in[6];   // [1024,1024]
    const float* wq_b  = (const float*)d_in[7];
    const float* wk_w  = (const float*)d_in[8];
    const float* wk_b  = (const float*)d_in[9];
    const float* wv_w  = (const float*)d_in[10];
    const float* wv_b  = (const float*)d_in[11];

    float* out   = (float*)d_out;
    float* h_new = out;                 // [64,1024]
    float* c_new = out + 64 * 1024;     // [64,1024,1024]

    // ws layout: part (bf16) | act (f32) | hpart (f32) | cnt (u32 x 96)
    unsigned short* part = (unsigned short*)d_ws;          // 8*64*6144 ushorts
    float* act   = (float*)(part + (size_t)8 * 64 * NCOL); // 64*6144 floats
    float* hpart = act + (size_t)64 * NCOL;                // 64*16*1024 floats
    unsigned int* cnt = (unsigned int*)(hpart + (size_t)64 * 16 * 1024);

    hipMemsetAsync(cnt, 0, 96 * sizeof(unsigned int), stream);

    proj_kernel<<<576, 256, 0, stream>>>(input, hvec, w_ih, w_hh,
                                         wq_w, wk_w, wv_w, bias,
                                         wq_b, wk_b, wv_b, part, act, cnt);
    update_kernel<<<dim3(16, 64), 256, 0, stream>>>(c_in, act, c_new, hpart);
    readout_kernel<<<(64 * 1024) / 256, 256, 0, stream>>>(hpart, act, h_new);
}

// Round 14
// 119.083 us; speedup vs baseline: 1.8888x; 1.8888x over previous
//
#include <hip/hip_runtime.h>
#include <hip/hip_bf16.h>
#include <cstdint>

// Problem: B=64, D=1024, H=1024.
// act columns (6144): [0,1024) i_g | [1024,2048) f_g | [2048,3072) o_g
//                     [3072,4096) q | [4096,5120) k  | [5120,6144) v
// part layout (bf16): part[c][b][j], c = K-chunk of 256 (gates: 8 chunks;
// qkv: chunks 0..3 only)

#define NCOL 6144

typedef __attribute__((ext_vector_type(8))) short short8;
typedef __attribute__((ext_vector_type(4))) float f32x4;
typedef __attribute__((ext_vector_type(4))) unsigned short u16x4;

static __device__ __forceinline__ unsigned short f2bs(float f) {
    union { __hip_bfloat16 h; unsigned short s; } cv;
    cv.h = __float2bfloat16(f);          // RNE
    return cv.s;
}
static __device__ __forceinline__ u16x4 cvt4(f32x4 x) {
    u16x4 u; u[0]=f2bs(x[0]); u[1]=f2bs(x[1]); u[2]=f2bs(x[2]); u[3]=f2bs(x[3]);
    return u;
}
static __device__ __forceinline__ float b2f(unsigned short s) {
    union { uint32_t u; float f; } v; v.u = ((uint32_t)s) << 16; return v.f;
}

// ---------------- Kernel P: projections via bf16 MFMA (partial-K GEMM) ------
// R9-proven: flat 576-block grid, dbuf K=64 sub-steps, native cvt, bf16 part.
__global__ __launch_bounds__(256) void proj_kernel(
    const float* __restrict__ input, const float* __restrict__ hvec,
    const float* __restrict__ w_ih, const float* __restrict__ w_hh,
    const float* __restrict__ wq, const float* __restrict__ wk,
    const float* __restrict__ wv, unsigned short* __restrict__ part)
{
    int bid = blockIdx.x;           // 0..575 (384 gate items + 192 qkv items)
    int ct, c;
    if (bid < 384) { ct = bid >> 3; c = bid & 7; }
    else { int e = bid - 384; ct = 48 + (e >> 2); c = e & 3; }
    int jbase = ct * 64;
    int o = jbase >> 10;            // 0..5
    int jloc = jbase & 1023;

    const float* W; const float* src; int koff; int wrow;
    if (o < 3) {
        wrow = o * 1024 + jloc;
        if (c < 4) { W = w_ih; src = input; koff = c * 256; }
        else       { W = w_hh; src = hvec;  koff = (c - 4) * 256; }
    } else {
        wrow = jloc;
        W = (o == 3) ? wq : (o == 4) ? wk : wv;
        src = input; koff = c * 256;
    }

    // bf16 sub-tiles [64 rows][64 K + 8 pad], double-buffered
    __shared__ unsigned short Als[2][64][72];
    __shared__ unsigned short Bls[2][64][72];

    int tid = threadIdx.x;
    int r0 = tid >> 4;              // staging row base 0..15 (+16*i)
    int kc = (tid & 15) << 2;       // float col 0..60

    f32x4 ra[4], rb[4];

    // prefetch sub-step 0
    #pragma unroll
    for (int i = 0; i < 4; ++i)
        ra[i] = *(const f32x4*)&src[(size_t)(r0 + 16 * i) * 1024 + koff + kc];
    #pragma unroll
    for (int i = 0; i < 4; ++i)
        rb[i] = *(const f32x4*)&W[(size_t)(wrow + r0 + 16 * i) * 1024 + koff + kc];
    #pragma unroll
    for (int i = 0; i < 4; ++i) *(u16x4*)&Als[0][r0 + 16 * i][kc] = cvt4(ra[i]);
    #pragma unroll
    for (int i = 0; i < 4; ++i) *(u16x4*)&Bls[0][r0 + 16 * i][kc] = cvt4(rb[i]);
    __syncthreads();

    int lane = tid & 63;
    int w    = tid >> 6;                    // wave -> col group
    int cn16 = lane & 15;
    int kg   = lane >> 4;                   // 0..3

    f32x4 acc[4];
    #pragma unroll
    for (int m = 0; m < 4; ++m) { acc[m][0]=0.f; acc[m][1]=0.f; acc[m][2]=0.f; acc[m][3]=0.f; }

    #pragma unroll
    for (int s = 0; s < 4; ++s) {
        if (s < 3) {                        // issue next sub-slab loads first
            int kof2 = koff + (s + 1) * 64 + kc;
            #pragma unroll
            for (int i = 0; i < 4; ++i)
                ra[i] = *(const f32x4*)&src[(size_t)(r0 + 16 * i) * 1024 + kof2];
            #pragma unroll
            for (int i = 0; i < 4; ++i)
                rb[i] = *(const f32x4*)&W[(size_t)(wrow + r0 + 16 * i) * 1024 + kof2];
        }

        int buf = s & 1;
        #pragma unroll
        for (int ks2 = 0; ks2 < 2; ++ks2) {
            int kb = ks2 * 32 + kg * 8;     // 16B-aligned
            short8 bf = *(const short8*)&Bls[buf][w * 16 + cn16][kb];
            #pragma unroll
            for (int m = 0; m < 4; ++m) {
                short8 af = *(const short8*)&Als[buf][m * 16 + cn16][kb];
                acc[m] = __builtin_amdgcn_mfma_f32_16x16x32_bf16(af, bf, acc[m], 0, 0, 0);
            }
        }

        if (s < 3) {
            int nb = (s + 1) & 1;
            #pragma unroll
            for (int i = 0; i < 4; ++i) *(u16x4*)&Als[nb][r0 + 16 * i][kc] = cvt4(ra[i]);
            #pragma unroll
            for (int i = 0; i < 4; ++i) *(u16x4*)&Bls[nb][r0 + 16 * i][kc] = cvt4(rb[i]);
        }
        __syncthreads();
    }

    // D layout: col = lane&15, row(batch) = kg*4 + reg (+ m*16); bf16 store
    #pragma unroll
    for (int m = 0; m < 4; ++m) {
        #pragma unroll
        for (int r = 0; r < 4; ++r) {
            int b = m * 16 + kg * 4 + r;
            part[((size_t)c * 64 + b) * NCOL + jbase + w * 16 + cn16] = f2bs(acc[m][r]);
        }
    }
}

// ---------------- Kernel A: reduce chunks + bias + activation ----------------
__global__ __launch_bounds__(256) void act_kernel(
    const unsigned short* __restrict__ part, const float* __restrict__ bias,
    const float* __restrict__ wq_b, const float* __restrict__ wk_b,
    const float* __restrict__ wv_b, float* __restrict__ act)
{
    int idx4 = blockIdx.x * 256 + threadIdx.x;   // 0..64*6144/4
    int b = idx4 / (NCOL / 4);
    int j = (idx4 - b * (NCOL / 4)) * 4;
    int nc = (j < 3072) ? 8 : 4;
    f32x4 s; s[0]=0.f; s[1]=0.f; s[2]=0.f; s[3]=0.f;
    for (int cc = 0; cc < nc; ++cc) {
        u16x4 u = *(const u16x4*)&part[((size_t)cc * 64 + b) * NCOL + j];
        s[0] += b2f(u[0]); s[1] += b2f(u[1]); s[2] += b2f(u[2]); s[3] += b2f(u[3]);
    }
    const float* bp;
    if (j < 3072) bp = bias + j;
    else if (j < 4096) bp = wq_b + (j - 3072);
    else if (j < 5120) bp = wk_b + (j - 4096);
    else bp = wv_b + (j - 5120);
    s += *(const f32x4*)bp;
    f32x4 r;
    if (j < 2048) {
        r[0] = expf(s[0]); r[1] = expf(s[1]); r[2] = expf(s[2]); r[3] = expf(s[3]);
    } else if (j < 3072) {
        r[0] = 1.f/(1.f+expf(-s[0])); r[1] = 1.f/(1.f+expf(-s[1]));
        r[2] = 1.f/(1.f+expf(-s[2])); r[3] = 1.f/(1.f+expf(-s[3]));
    } else {
        r = s;
    }
    *(f32x4*)&act[(size_t)b * NCOL + j] = r;
}

// ---------------- Kernel U: c_new = f*c + (i*v)*k, fused q-weighted row sums -
// grid: (16 row-tiles of 64, 64 batches), 256 threads, 4 cols/thread.
// R12-proven: grouped 8-load / 8-store nt phases (8x fewer DRAM turnarounds).
__global__ __launch_bounds__(256) void update_kernel(
    const float* __restrict__ c_in, const float* __restrict__ act,
    float* __restrict__ c_out, float* __restrict__ hpart)
{
    int t = blockIdx.x;            // 0..15
    int b = blockIdx.y;            // 0..63
    int tid = threadIdx.x;
    const float* arow = act + (size_t)b * NCOL;

    __shared__ float fs[64], ivs[64], qvs[64];
    if (tid < 64) {
        int hrow = t * 64 + tid;
        fs[tid]  = arow[1024 + hrow];
        ivs[tid] = arow[hrow] * arow[5120 + hrow];
        qvs[tid] = arow[3072 + hrow];
    }
    int col = tid * 4;
    f32x4 k4 = *(const f32x4*)&arow[4096 + col];
    __syncthreads();

    f32x4 acc; acc[0]=0.f; acc[1]=0.f; acc[2]=0.f; acc[3]=0.f;
    size_t base = ((size_t)b * 1024 + (size_t)t * 64) * 1024 + col;

    f32x4 cc[8];
    for (int g = 0; g < 8; ++g) {
        size_t gb = base + (size_t)g * 8 * 1024;
        #pragma unroll
        for (int i = 0; i < 8; ++i)
            cc[i] = __builtin_nontemporal_load((const f32x4*)(c_in + gb + (size_t)i * 1024));
        #pragma unroll
        for (int i = 0; i < 8; ++i) {
            int hh = g * 8 + i;
            float f = fs[hh], iv = ivs[hh], qv = qvs[hh];
            f32x4 cn = f * cc[i] + iv * k4;
            __builtin_nontemporal_store(cn, (f32x4*)(c_out + gb + (size_t)i * 1024));
            acc += qv * cn;
        }
    }
    *(f32x4*)&hpart[((size_t)b * 16 + t) * 1024 + col] = acc;
}

// ---------------- Kernel R: h_new = o_g * sum_t hpart ----------------
__global__ __launch_bounds__(256) void readout_kernel(
    const float* __restrict__ hpart, const float* __restrict__ act,
    float* __restrict__ h_new)
{
    int idx = blockIdx.x * 256 + threadIdx.x;   // 0..65536
    int b = idx >> 10, j = idx & 1023;
    float s = 0.f;
    #pragma unroll
    for (int t = 0; t < 16; ++t)
        s += hpart[((size_t)b * 16 + t) * 1024 + j];
    h_new[idx] = act[(size_t)b * NCOL + 2048 + j] * s;
}

extern "C" void kernel_launch(void* const* d_in, const int* in_sizes, int n_in,
                              void* d_out, int out_size, void* d_ws, size_t ws_size,
                              hipStream_t stream)
{
    (void)in_sizes; (void)n_in; (void)out_size; (void)ws_size;
    const float* input = (const float*)d_in[0];   // [64,1024]
    const float* hvec  = (const float*)d_in[1];   // [64,1024]
    const float* c_in  = (const float*)d_in[2];   // [64,1024,1024]
    const float* w_ih  = (const float*)d_in[3];   // [3072,1024]
    const float* w_hh  = (const float*)d_in[4];   // [3072,1024]
    const float* bias  = (const float*)d_in[5];   // [3072]
    const float* wq_w  = (const float*)d_in[6];   // [1024,1024]
    const float* wq_b  = (const float*)d_in[7];
    const float* wk_w  = (const float*)d_in[8];
    const float* wk_b  = (const float*)d_in[9];
    const float* wv_w  = (const float*)d_in[10];
    const float* wv_b  = (const float*)d_in[11];

    float* out   = (float*)d_out;
    float* h_new = out;                 // [64,1024]
    float* c_new = out + 64 * 1024;     // [64,1024,1024]

    // ws layout: part (bf16) | act (f32) | hpart (f32)
    unsigned short* part = (unsigned short*)d_ws;          // 8*64*6144 ushorts
    float* act   = (float*)(part + (size_t)8 * 64 * NCOL); // 64*6144 floats
    float* hpart = act + (size_t)64 * NCOL;                // 64*16*1024 floats

    proj_kernel<<<576, 256, 0, stream>>>(input, hvec, w_ih, w_hh,
                                         wq_w, wk_w, wv_w, part);
    act_kernel<<<(64 * NCOL / 4) / 256, 256, 0, stream>>>(part, bias, wq_b, wk_b,
                                                          wv_b, act);
    update_kernel<<<dim3(16, 64), 256, 0, stream>>>(c_in, act, c_new, hpart);
    readout_kernel<<<(64 * 1024) / 256, 256, 0, stream>>>(hpart, act, h_new);
}